// Round 1
// baseline (10727.962 us; speedup 1.0000x reference)
//
#include <hip/hip_runtime.h>
#include <hip/hip_bf16.h>
#include <cstdint>
#include <cstddef>

#define B_ 128
#define T_ 256
#define H_ 1024
#define V_ 2048

using short8 = __attribute__((ext_vector_type(8))) short;
using f32x4  = __attribute__((ext_vector_type(4))) float;

// ---------- helpers ----------
__device__ __forceinline__ unsigned short f2bf(float f) {
  unsigned u = __builtin_bit_cast(unsigned, f);
  u += 0x7FFFu + ((u >> 16) & 1u);   // RNE
  return (unsigned short)(u >> 16);
}
__device__ __forceinline__ float bf2f(unsigned short h) {
  return __builtin_bit_cast(float, (unsigned)h << 16);
}

typedef __attribute__((address_space(3))) void       lds_void;
typedef __attribute__((address_space(1))) const void gbl_void;

__device__ __forceinline__ void async16(const void* g, void* l) {
  // 16B-wide direct global->LDS (dest = wave-uniform base + lane*16)
  __builtin_amdgcn_global_load_lds((gbl_void*)g, (lds_void*)l, 16, 0, 0);
}

// Per-group spin barrier across the 32 column-slice blocks of a batch group.
// Monotone counter, agent scope (correct across XCDs).
__device__ __forceinline__ void group_barrier(unsigned int* slot, unsigned target) {
  __threadfence();              // release: make our global stores visible (agent)
  __syncthreads();
  if (threadIdx.x == 0) {
    __hip_atomic_fetch_add(slot, 1u, __ATOMIC_RELEASE, __HIP_MEMORY_SCOPE_AGENT);
    while (__hip_atomic_load(slot, __ATOMIC_ACQUIRE, __HIP_MEMORY_SCOPE_AGENT) < target)
      __builtin_amdgcn_s_sleep(2);
  }
  __syncthreads();
  __threadfence();              // acquire side for all threads
}

// ---------- kernel 1: Wd (fp32 [H][V]) -> WdT (bf16 [V][H]) ----------
__global__ void wd_transpose(const float* __restrict__ Wd, unsigned short* __restrict__ WdT) {
  __shared__ float tile[64][65];
  const int k0 = blockIdx.x * 64;       // 16 blocks over K=1024
  const int n0 = blockIdx.y * 64;       // 32 blocks over N=2048
  const int c = threadIdx.x & 63, r4 = threadIdx.x >> 6;
#pragma unroll
  for (int i = 0; i < 16; ++i) {
    int r = i * 4 + r4;
    tile[r][c] = Wd[(size_t)(k0 + r) * V_ + n0 + c];
  }
  __syncthreads();
#pragma unroll
  for (int i = 0; i < 16; ++i) {
    int n = i * 4 + r4;
    WdT[(size_t)(n0 + n) * H_ + k0 + c] = f2bf(tile[c][n]);
  }
}

// ---------- kernel 2: persistent recurrence ----------
// Grid: 256 blocks x 256 threads. Block (g = blockIdx&7, s = blockIdx>>3)
// owns batch rows [16g,16g+16) x hidden cols [32s,32s+32).
// Wh slice (hi/lo bf16) lives in VGPRs; 4 waves split K=1024.
__global__ __launch_bounds__(256, 1) void rnn_recur(
    const int* __restrict__ inputs, const float* __restrict__ state,
    const float* __restrict__ Wx, const float* __restrict__ Wh,
    const float* __restrict__ bias, unsigned short* __restrict__ Yb,
    float* __restrict__ hfinal, unsigned int* __restrict__ bar)
{
  const int tid  = threadIdx.x;
  const int wave = tid >> 6, lane = tid & 63;
  const int g    = blockIdx.x & 7;
  const int s    = blockIdx.x >> 3;
  const int c0   = s * 32;
  const int row0 = g * 16;

  __shared__ float stage[256 * 32];   // 32KB staging for Wh slice (one K-quarter)
  __shared__ float red[4][16][32];    // 8KB cross-wave reduction

  short8 Bf[8][2][2];                 // [k-chunk][col-tile][hi/lo] -> 128 VGPRs

  // ---- prologue: build Wh B-fragments (hi/lo bf16) ----
  for (int p = 0; p < 4; ++p) {       // pass p stages k in [256p, 256p+256)
    for (int it = 0; it < 32; ++it) {
      int kk = it * 8 + (tid >> 5);
      stage[kk * 32 + (tid & 31)] = Wh[(size_t)(p * 256 + kk) * H_ + c0 + (tid & 31)];
    }
    __syncthreads();
    if (wave == p) {                  // wave w owns k range [256w, 256w+256)
#pragma unroll
      for (int ch = 0; ch < 8; ++ch) {
#pragma unroll
        for (int ct = 0; ct < 2; ++ct) {
          short8 hi, lo;
#pragma unroll
          for (int j = 0; j < 8; ++j) {
            int kk = ch * 32 + ((lane >> 4) * 8) + j;
            float f = stage[kk * 32 + ct * 16 + (lane & 15)];
            unsigned short h16 = f2bf(f);
            hi[j] = (short)h16;
            lo[j] = (short)f2bf(f - bf2f(h16));
          }
          Bf[ch][ct][0] = hi;
          Bf[ch][ct][1] = lo;
        }
      }
    }
    __syncthreads();
  }

  // Yb[0] = bf16(state) for this block's (rows x cols) tile
  for (int i = tid; i < 512; i += 256) {
    int r = i >> 5, c = i & 31;
    Yb[(size_t)(row0 + r) * H_ + c0 + c] = f2bf(state[(size_t)(row0 + r) * H_ + c0 + c]);
  }

  unsigned int* slot = bar + g * 16;  // 64B-spaced counters
  group_barrier(slot, 32u);

  const int r0    = tid >> 5;                     // 0..7
  const int cc    = tid & 31;
  const int arow  = row0 + (lane & 15);
  const int kbase = wave * 256 + ((lane >> 4) * 8);

  for (int t = 0; t < T_; ++t) {
    // embedding gather (independent of barrier; overlaps MFMA)
    int tok0 = inputs[(row0 + r0) * T_ + t];
    int tok1 = inputs[(row0 + 8 + r0) * T_ + t];
    float e0 = Wx[(size_t)tok0 * H_ + c0 + cc];
    float e1 = Wx[(size_t)tok1 * H_ + c0 + cc];

    // A fragments: h_t rows straight from global (bf16)
    const unsigned short* hp = Yb + (size_t)t * (B_ * H_) + (size_t)arow * H_ + kbase;
    short8 A[8];
#pragma unroll
    for (int ch = 0; ch < 8; ++ch)
      A[ch] = *(const short8*)(hp + ch * 32);

    f32x4 acc0 = {0.f, 0.f, 0.f, 0.f}, acc1 = {0.f, 0.f, 0.f, 0.f};
#pragma unroll
    for (int ch = 0; ch < 8; ++ch) {
      acc0 = __builtin_amdgcn_mfma_f32_16x16x32_bf16(A[ch], Bf[ch][0][0], acc0, 0, 0, 0);
      acc1 = __builtin_amdgcn_mfma_f32_16x16x32_bf16(A[ch], Bf[ch][1][0], acc1, 0, 0, 0);
      acc0 = __builtin_amdgcn_mfma_f32_16x16x32_bf16(A[ch], Bf[ch][0][1], acc0, 0, 0, 0);
      acc1 = __builtin_amdgcn_mfma_f32_16x16x32_bf16(A[ch], Bf[ch][1][1], acc1, 0, 0, 0);
    }

    // cross-wave K reduction via LDS
#pragma unroll
    for (int r = 0; r < 4; ++r) {
      red[wave][(lane >> 4) * 4 + r][lane & 15]      = acc0[r];
      red[wave][(lane >> 4) * 4 + r][16 + (lane & 15)] = acc1[r];
    }
    __syncthreads();

    float v0 = red[0][r0][cc] + red[1][r0][cc] + red[2][r0][cc] + red[3][r0][cc]
             + e0 + bias[c0 + cc];
    float v1 = red[0][8 + r0][cc] + red[1][8 + r0][cc] + red[2][8 + r0][cc] + red[3][8 + r0][cc]
             + e1 + bias[c0 + cc];
    float h0 = tanhf(v0), h1 = tanhf(v1);

    size_t obase = (size_t)(t + 1) * (B_ * H_);
    Yb[obase + (size_t)(row0 + r0) * H_ + c0 + cc]     = f2bf(h0);
    Yb[obase + (size_t)(row0 + 8 + r0) * H_ + c0 + cc] = f2bf(h1);

    if (t == T_ - 1) {
      hfinal[(size_t)(row0 + r0) * H_ + c0 + cc]     = h0;
      hfinal[(size_t)(row0 + 8 + r0) * H_ + c0 + cc] = h1;
    } else {
      group_barrier(slot, 32u * (unsigned)(t + 2));
    }
  }
}

// ---------- kernel 3: projection GEMM ----------
// out[32768][2048] = A(bf16 [32768][1024]) @ WdT^T + bd, m97-style 128x128 tile.
__global__ __launch_bounds__(256, 2) void proj_gemm(
    const unsigned short* __restrict__ A,   // Yb + B*H
    const unsigned short* __restrict__ Bt,  // [2048][1024] bf16
    const float* __restrict__ bd, float* __restrict__ out)
{
  const int tid = threadIdx.x;
  const int wave = tid >> 6, lane = tid & 63;
  const int wm = wave >> 1, wn = wave & 1;      // 2x2 wave grid, 64x64 per wave
  const int m0 = blockIdx.y * 128, n0 = blockIdx.x * 128;

  __shared__ unsigned short As[128 * 32];
  __shared__ unsigned short Bs[128 * 32];

  f32x4 acc[4][4];
#pragma unroll
  for (int i = 0; i < 4; ++i)
#pragma unroll
    for (int j = 0; j < 4; ++j)
      acc[i][j] = (f32x4){0.f, 0.f, 0.f, 0.f};

  const int lrow = tid >> 2;                    // 0..63
  const int lcol = (tid & 3) * 16;              // byte offset in 64B row

  for (int k0 = 0; k0 < H_; k0 += 32) {
    __syncthreads();  // prior ds_reads done before overwrite
    async16((const char*)(A  + (size_t)(m0 + lrow)      * H_ + k0) + lcol, (char*)As + tid * 16);
    async16((const char*)(A  + (size_t)(m0 + 64 + lrow) * H_ + k0) + lcol, (char*)As + 4096 + tid * 16);
    async16((const char*)(Bt + (size_t)(n0 + lrow)      * H_ + k0) + lcol, (char*)Bs + tid * 16);
    async16((const char*)(Bt + (size_t)(n0 + 64 + lrow) * H_ + k0) + lcol, (char*)Bs + 4096 + tid * 16);
    __syncthreads();  // compiler drains vmcnt before barrier

    short8 af[4], bf[4];
#pragma unroll
    for (int i = 0; i < 4; ++i) {
      af[i] = *(const short8*)(As + (wm * 64 + i * 16 + (lane & 15)) * 32 + (lane >> 4) * 8);
      bf[i] = *(const short8*)(Bs + (wn * 64 + i * 16 + (lane & 15)) * 32 + (lane >> 4) * 8);
    }
#pragma unroll
    for (int i = 0; i < 4; ++i)
#pragma unroll
      for (int j = 0; j < 4; ++j)
        acc[i][j] = __builtin_amdgcn_mfma_f32_16x16x32_bf16(af[i], bf[j], acc[i][j], 0, 0, 0);
  }

#pragma unroll
  for (int i = 0; i < 4; ++i) {
#pragma unroll
    for (int j = 0; j < 4; ++j) {
      int n = n0 + wn * 64 + j * 16 + (lane & 15);
      float bv = bd[n];
#pragma unroll
      for (int r = 0; r < 4; ++r) {
        int m = m0 + wm * 64 + i * 16 + (lane >> 4) * 4 + r;
        out[(size_t)m * V_ + n] = acc[i][j][r] + bv;   // C layout: row=(l>>4)*4+r, col=l&15
      }
    }
  }
}

// ---------- workspace layout ----------
static constexpr size_t YB_BYTES  = (size_t)(T_ + 1) * B_ * H_ * 2;  // 67,371,008
static constexpr size_t WDT_OFF   = YB_BYTES;
static constexpr size_t WDT_BYTES = (size_t)V_ * H_ * 2;             // 4,194,304
static constexpr size_t BAR_OFF   = WDT_OFF + WDT_BYTES;

extern "C" void kernel_launch(void* const* d_in, const int* in_sizes, int n_in,
                              void* d_out, int out_size, void* d_ws, size_t ws_size,
                              hipStream_t stream) {
  const int*   inputs = (const int*)d_in[0];
  const float* state  = (const float*)d_in[1];
  const float* Wx     = (const float*)d_in[2];
  const float* Wh     = (const float*)d_in[3];
  const float* b      = (const float*)d_in[4];
  const float* Wd     = (const float*)d_in[5];
  const float* bd     = (const float*)d_in[6];

  float* out    = (float*)d_out;
  float* hfinal = out + (size_t)T_ * B_ * V_;

  unsigned short* Yb  = (unsigned short*)d_ws;
  unsigned short* WdT = (unsigned short*)((char*)d_ws + WDT_OFF);
  unsigned int*   bar = (unsigned int*)((char*)d_ws + BAR_OFF);

  hipMemsetAsync(bar, 0, 512, stream);                       // ws is 0xAA-poisoned each call
  wd_transpose<<<dim3(16, 32), 256, 0, stream>>>(Wd, WdT);
  rnn_recur<<<256, 256, 0, stream>>>(inputs, state, Wx, Wh, b, Yb, hfinal, bar);
  proj_gemm<<<dim3(16, 256), 256, 0, stream>>>(Yb + (size_t)B_ * H_, WdT, bd, out);
}

// Round 2
// 2510.714 us; speedup vs baseline: 4.2729x; 4.2729x over previous
//
#include <hip/hip_runtime.h>
#include <hip/hip_bf16.h>
#include <cstdint>
#include <cstddef>

#define B_ 128
#define T_ 256
#define H_ 1024
#define V_ 2048

using short8 = __attribute__((ext_vector_type(8))) short;
using f32x4  = __attribute__((ext_vector_type(4))) float;

// ---------- helpers ----------
__device__ __forceinline__ unsigned short f2bf(float f) {
  unsigned u = __builtin_bit_cast(unsigned, f);
  u += 0x7FFFu + ((u >> 16) & 1u);   // RNE
  return (unsigned short)(u >> 16);
}
__device__ __forceinline__ float bf2f(unsigned short h) {
  return __builtin_bit_cast(float, (unsigned)h << 16);
}

typedef __attribute__((address_space(3))) void       lds_void;
typedef __attribute__((address_space(1))) const void gbl_void;

__device__ __forceinline__ void async16(const void* g, void* l) {
  __builtin_amdgcn_global_load_lds((gbl_void*)g, (lds_void*)l, 16, 0, 0);
}

// Per-group flag barrier: each of the 32 col-slice blocks publishes its own
// 128B-spaced epoch flag with ONE release store (no contended RMW). Wave 0
// detects completion with a single 32-lane gather + ballot, then issues one
// agent-scope acquire fence.
__device__ __forceinline__ void flag_barrier(unsigned* fl, int s, unsigned epoch,
                                             int wave, int lane) {
  __syncthreads();   // all waves' h-stores drained (compiler emits vmcnt(0))
  if (threadIdx.x == 0)
    __hip_atomic_store(fl + s * 32, epoch, __ATOMIC_RELEASE, __HIP_MEMORY_SCOPE_AGENT);
  if (wave == 0) {
    unsigned f;
    do {
      f = __hip_atomic_load(fl + (lane & 31) * 32, __ATOMIC_RELAXED, __HIP_MEMORY_SCOPE_AGENT);
    } while (__ballot(f >= epoch) != ~0ull);
    __builtin_amdgcn_fence(__ATOMIC_ACQUIRE, "agent");
  }
  __syncthreads();
}

// ---------- kernel 1: Wd (fp32 [H][V]) -> WdT (bf16 [V][H]) ----------
__global__ void wd_transpose(const float* __restrict__ Wd, unsigned short* __restrict__ WdT) {
  __shared__ float tile[64][65];
  const int k0 = blockIdx.x * 64;
  const int n0 = blockIdx.y * 64;
  const int c = threadIdx.x & 63, r4 = threadIdx.x >> 6;
#pragma unroll
  for (int i = 0; i < 16; ++i) {
    int r = i * 4 + r4;
    tile[r][c] = Wd[(size_t)(k0 + r) * V_ + n0 + c];
  }
  __syncthreads();
#pragma unroll
  for (int i = 0; i < 16; ++i) {
    int n = i * 4 + r4;
    WdT[(size_t)(n0 + n) * H_ + k0 + c] = f2bf(tile[c][n]);
  }
}

// ---------- kernel 2: persistent recurrence ----------
// Grid: 256 blocks x 256 threads. Block (g = blockIdx&7, s = blockIdx>>3)
// owns batch rows [16g,16g+16) x hidden cols [32s,32s+32).
// Wh slice (hi/lo bf16) lives in VGPRs; 4 waves split K=1024.
__global__ __launch_bounds__(256, 1) void rnn_recur(
    const int* __restrict__ inputs, const float* __restrict__ state,
    const float* __restrict__ Wx, const float* __restrict__ Wh,
    const float* __restrict__ bias, unsigned short* __restrict__ Yb,
    float* __restrict__ hfinal, unsigned int* __restrict__ flags)
{
  const int tid  = threadIdx.x;
  const int wave = tid >> 6, lane = tid & 63;
  const int g    = blockIdx.x & 7;
  const int s    = blockIdx.x >> 3;
  const int c0   = s * 32;
  const int row0 = g * 16;

  __shared__ float stage[256 * 32];   // 32KB staging for Wh slice (one K-quarter)
  __shared__ float red[4][16][32];    // 8KB cross-wave reduction

  short8 Bf[8][2][2];                 // [k-chunk][col-tile][hi/lo] -> 128 VGPRs

  // ---- prologue: build Wh B-fragments (hi/lo bf16) ----
  for (int p = 0; p < 4; ++p) {
    for (int it = 0; it < 32; ++it) {
      int kk = it * 8 + (tid >> 5);
      stage[kk * 32 + (tid & 31)] = Wh[(size_t)(p * 256 + kk) * H_ + c0 + (tid & 31)];
    }
    __syncthreads();
    if (wave == p) {
#pragma unroll
      for (int ch = 0; ch < 8; ++ch) {
#pragma unroll
        for (int ct = 0; ct < 2; ++ct) {
          short8 hi, lo;
#pragma unroll
          for (int j = 0; j < 8; ++j) {
            int kk = ch * 32 + ((lane >> 4) * 8) + j;
            float f = stage[kk * 32 + ct * 16 + (lane & 15)];
            unsigned short h16 = f2bf(f);
            hi[j] = (short)h16;
            lo[j] = (short)f2bf(f - bf2f(h16));
          }
          Bf[ch][ct][0] = hi;
          Bf[ch][ct][1] = lo;
        }
      }
    }
    __syncthreads();
  }

  // Yb[0] = bf16(state) for this block's tile
  for (int i = tid; i < 512; i += 256) {
    int r = i >> 5, c = i & 31;
    Yb[(size_t)(row0 + r) * H_ + c0 + c] = f2bf(state[(size_t)(row0 + r) * H_ + c0 + c]);
  }

  unsigned int* fl = flags + g * 32 * 32;   // 32 flags x 128B spacing per group

  const int r0    = tid >> 5;                     // 0..7
  const int cc    = tid & 31;
  const int arow  = row0 + (lane & 15);
  const int kbase = wave * 256 + ((lane >> 4) * 8);

  const float bv0 = bias[c0 + cc];                // loop-invariant

  // prefetch embedding for t=0 (independent of barrier)
  int   tk0 = inputs[(row0 + r0) * T_ + 0];
  int   tk1 = inputs[(row0 + 8 + r0) * T_ + 0];
  float e0  = Wx[(size_t)tk0 * H_ + c0 + cc];
  float e1  = Wx[(size_t)tk1 * H_ + c0 + cc];

  flag_barrier(fl, s, 1u, wave, lane);            // publish state tile (epoch 1)

  for (int t = 0; t < T_; ++t) {
    // A fragments: h_t rows straight from global (bf16)
    const unsigned short* hp = Yb + (size_t)t * (B_ * H_) + (size_t)arow * H_ + kbase;
    short8 A[8];
#pragma unroll
    for (int ch = 0; ch < 8; ++ch)
      A[ch] = *(const short8*)(hp + ch * 32);

    f32x4 acc0 = {0.f, 0.f, 0.f, 0.f}, acc1 = {0.f, 0.f, 0.f, 0.f};
#pragma unroll
    for (int ch = 0; ch < 8; ++ch) {
      acc0 = __builtin_amdgcn_mfma_f32_16x16x32_bf16(A[ch], Bf[ch][0][0], acc0, 0, 0, 0);
      acc1 = __builtin_amdgcn_mfma_f32_16x16x32_bf16(A[ch], Bf[ch][1][0], acc1, 0, 0, 0);
      acc0 = __builtin_amdgcn_mfma_f32_16x16x32_bf16(A[ch], Bf[ch][0][1], acc0, 0, 0, 0);
      acc1 = __builtin_amdgcn_mfma_f32_16x16x32_bf16(A[ch], Bf[ch][1][1], acc1, 0, 0, 0);
    }

    // cross-wave K reduction via LDS
#pragma unroll
    for (int r = 0; r < 4; ++r) {
      red[wave][(lane >> 4) * 4 + r][lane & 15]        = acc0[r];
      red[wave][(lane >> 4) * 4 + r][16 + (lane & 15)] = acc1[r];
    }
    __syncthreads();

    float v0 = red[0][r0][cc] + red[1][r0][cc] + red[2][r0][cc] + red[3][r0][cc] + e0 + bv0;
    float v1 = red[0][8 + r0][cc] + red[1][8 + r0][cc] + red[2][8 + r0][cc] + red[3][8 + r0][cc]
             + e1 + bv0;
    float h0 = tanhf(v0), h1 = tanhf(v1);

    size_t obase = (size_t)(t + 1) * (B_ * H_);
    Yb[obase + (size_t)(row0 + r0) * H_ + c0 + cc]     = f2bf(h0);
    Yb[obase + (size_t)(row0 + 8 + r0) * H_ + c0 + cc] = f2bf(h1);

    if (t == T_ - 1) {
      hfinal[(size_t)(row0 + r0) * H_ + c0 + cc]     = h0;
      hfinal[(size_t)(row0 + 8 + r0) * H_ + c0 + cc] = h1;
    } else {
      // prefetch next step's embedding BEFORE the wait (hides under the spin)
      tk0 = inputs[(row0 + r0) * T_ + t + 1];
      tk1 = inputs[(row0 + 8 + r0) * T_ + t + 1];
      e0  = Wx[(size_t)tk0 * H_ + c0 + cc];
      e1  = Wx[(size_t)tk1 * H_ + c0 + cc];
      flag_barrier(fl, s, (unsigned)(t + 2), wave, lane);
    }
  }
}

// ---------- kernel 3: projection GEMM ----------
__global__ __launch_bounds__(256, 2) void proj_gemm(
    const unsigned short* __restrict__ A,   // Yb + B*H
    const unsigned short* __restrict__ Bt,  // [2048][1024] bf16
    const float* __restrict__ bd, float* __restrict__ out)
{
  const int tid = threadIdx.x;
  const int wave = tid >> 6, lane = tid & 63;
  const int wm = wave >> 1, wn = wave & 1;
  const int m0 = blockIdx.y * 128, n0 = blockIdx.x * 128;

  __shared__ unsigned short As[128 * 32];
  __shared__ unsigned short Bs[128 * 32];

  f32x4 acc[4][4];
#pragma unroll
  for (int i = 0; i < 4; ++i)
#pragma unroll
    for (int j = 0; j < 4; ++j)
      acc[i][j] = (f32x4){0.f, 0.f, 0.f, 0.f};

  const int lrow = tid >> 2;
  const int lcol = (tid & 3) * 16;

  for (int k0 = 0; k0 < H_; k0 += 32) {
    __syncthreads();
    async16((const char*)(A  + (size_t)(m0 + lrow)      * H_ + k0) + lcol, (char*)As + tid * 16);
    async16((const char*)(A  + (size_t)(m0 + 64 + lrow) * H_ + k0) + lcol, (char*)As + 4096 + tid * 16);
    async16((const char*)(Bt + (size_t)(n0 + lrow)      * H_ + k0) + lcol, (char*)Bs + tid * 16);
    async16((const char*)(Bt + (size_t)(n0 + 64 + lrow) * H_ + k0) + lcol, (char*)Bs + 4096 + tid * 16);
    __syncthreads();

    short8 af[4], bf[4];
#pragma unroll
    for (int i = 0; i < 4; ++i) {
      af[i] = *(const short8*)(As + (wm * 64 + i * 16 + (lane & 15)) * 32 + (lane >> 4) * 8);
      bf[i] = *(const short8*)(Bs + (wn * 64 + i * 16 + (lane & 15)) * 32 + (lane >> 4) * 8);
    }
#pragma unroll
    for (int i = 0; i < 4; ++i)
#pragma unroll
      for (int j = 0; j < 4; ++j)
        acc[i][j] = __builtin_amdgcn_mfma_f32_16x16x32_bf16(af[i], bf[j], acc[i][j], 0, 0, 0);
  }

#pragma unroll
  for (int i = 0; i < 4; ++i) {
#pragma unroll
    for (int j = 0; j < 4; ++j) {
      int n = n0 + wn * 64 + j * 16 + (lane & 15);
      float bv = bd[n];
#pragma unroll
      for (int r = 0; r < 4; ++r) {
        int m = m0 + wm * 64 + i * 16 + (lane >> 4) * 4 + r;
        out[(size_t)m * V_ + n] = acc[i][j][r] + bv;
      }
    }
  }
}

// ---------- workspace layout ----------
static constexpr size_t YB_BYTES  = (size_t)(T_ + 1) * B_ * H_ * 2;  // 67,371,008
static constexpr size_t WDT_OFF   = YB_BYTES;
static constexpr size_t WDT_BYTES = (size_t)V_ * H_ * 2;             // 4,194,304
static constexpr size_t BAR_OFF   = WDT_OFF + WDT_BYTES;
static constexpr size_t BAR_BYTES = 8 * 32 * 128;                    // 32 KB flag area

extern "C" void kernel_launch(void* const* d_in, const int* in_sizes, int n_in,
                              void* d_out, int out_size, void* d_ws, size_t ws_size,
                              hipStream_t stream) {
  const int*   inputs = (const int*)d_in[0];
  const float* state  = (const float*)d_in[1];
  const float* Wx     = (const float*)d_in[2];
  const float* Wh     = (const float*)d_in[3];
  const float* b      = (const float*)d_in[4];
  const float* Wd     = (const float*)d_in[5];
  const float* bd     = (const float*)d_in[6];

  float* out    = (float*)d_out;
  float* hfinal = out + (size_t)T_ * B_ * V_;

  unsigned short* Yb    = (unsigned short*)d_ws;
  unsigned short* WdT   = (unsigned short*)((char*)d_ws + WDT_OFF);
  unsigned int*   flags = (unsigned int*)((char*)d_ws + BAR_OFF);

  hipMemsetAsync(flags, 0, BAR_BYTES, stream);   // ws is 0xAA-poisoned each call
  wd_transpose<<<dim3(16, 32), 256, 0, stream>>>(Wd, WdT);
  rnn_recur<<<256, 256, 0, stream>>>(inputs, state, Wx, Wh, b, Yb, hfinal, flags);
  proj_gemm<<<dim3(16, 256), 256, 0, stream>>>(Yb + (size_t)B_ * H_, WdT, bd, out);
}